// Round 8
// baseline (2205.917 us; speedup 1.0000x reference)
//
#include <hip/hip_runtime.h>

#define BB 4
#define NN 16384
#define CC 64
#define NPOINT 1024
#define NSAMPLE 32

#define FPS_T 1024
#define NCHUNK 256          // 64 points per chunk
#define NCELL 4096          // 16^3 Morton cells

#define REPEAT16(M) M(0) M(1) M(2) M(3) M(4) M(5) M(6) M(7) \
                    M(8) M(9) M(10) M(11) M(12) M(13) M(14) M(15)

// ---------------------------------------------------------------------------
// K1: Pruned FPS, global-radius bound, one wave-reduction per iteration,
// zero global loads in the iteration chain.
//  - Morton counting-sort into d_ws (float4 x,y,z,origidx) [phase 0 only];
//    x,y additionally scattered into LDS sxy[] (main-loop source).
//  - Wave wv owns chunks {wv+16k}; lane L owns point (g<<6)+L of each.
//    Per-lane state: dreg[16] (plain regs), z##k + tb##k (asm-pinned regs),
//    chunk AABB in lane-k registers.
//  - Prune: chunk active iff mind2(AABB,c) <= prev_winner_d*1.001
//    (chunk max d <= global max d -> exact-conservative skip).
//  - Per-lane best (d,tb) recomputed only when argmax chunk touched or an
//    exact-tie hazard was flagged; wave reduce = ONE f32 butterfly (+ rare
//    exact-tie u32 butterfly); winner lane writes coords to ubc (dbuf),
//    lane0 atomicMax key=(d|tb|wv) into slotk (4-deep buffer); ONE barrier.
// Bit-exact: contract(off), (dx*dx+dy*dy)+dz*dz order, min() no-op skips,
// ties -> smallest original index via tb=0x3FFF-orig everywhere.
// ---------------------------------------------------------------------------
__global__ __launch_bounds__(FPS_T) void fps_kernel(const float* __restrict__ xyz,
                                                    float* __restrict__ new_xyz,
                                                    float4* __restrict__ sorted) {
    #pragma clang fp contract(off)
    extern __shared__ char smem_raw[];
    unsigned long long* slotk = (unsigned long long*)smem_raw;   // [4]
    float4* ubc   = (float4*)(slotk + 4);                        // [2][16]
    int*    wsum  = (int*)(ubc + 32);                            // [16]
    float2* sxy   = (float2*)(wsum + 16);                        // [NN] 128KB
    int*    hist  = (int*)(sxy + NN);                            // [4096]

    const int b    = blockIdx.x;
    const int tid  = threadIdx.x;
    const int lane = tid & 63;
    const int wv   = tid >> 6;                  // 0..15
    const float* bx = xyz + (size_t)b * NN * 3;
    float4* sb = sorted + (size_t)b * NN;

    // ---------- phase 0a: histogram of Morton cell codes ----------
    #pragma unroll
    for (int j = 0; j < 4; ++j) hist[j * FPS_T + tid] = 0;
    __syncthreads();

    #pragma unroll
    for (int j = 0; j < 16; ++j) {
        const int p = j * FPS_T + tid;
        const float x = bx[p * 3 + 0], y = bx[p * 3 + 1], z = bx[p * 3 + 2];
        int cx = (int)(x * 16.0f); cx = cx > 15 ? 15 : (cx < 0 ? 0 : cx);
        int cy = (int)(y * 16.0f); cy = cy > 15 ? 15 : (cy < 0 ? 0 : cy);
        int cz = (int)(z * 16.0f); cz = cz > 15 ? 15 : (cz < 0 ? 0 : cz);
        int code = 0;
        #pragma unroll
        for (int i = 0; i < 4; ++i)
            code |= (((cx >> i) & 1) << (3 * i)) |
                    (((cy >> i) & 1) << (3 * i + 1)) |
                    (((cz >> i) & 1) << (3 * i + 2));
        atomicAdd(&hist[code], 1);
    }
    __syncthreads();

    // ---------- phase 0b: exclusive scan of hist ----------
    {
        const int h0 = hist[4 * tid + 0], h1 = hist[4 * tid + 1];
        const int h2 = hist[4 * tid + 2], h3 = hist[4 * tid + 3];
        const int s  = h0 + h1 + h2 + h3;
        int v = s;
        #pragma unroll
        for (int o = 1; o < 64; o <<= 1) {
            const int u = __shfl_up(v, o, 64);
            if (lane >= o) v += u;
        }
        if (lane == 63) wsum[wv] = v;
        __syncthreads();
        int base = 0;
        for (int w = 0; w < wv; ++w) base += wsum[w];
        const int e0 = base + v - s;
        hist[4 * tid + 0] = e0;
        hist[4 * tid + 1] = e0 + h0;
        hist[4 * tid + 2] = e0 + h0 + h1;
        hist[4 * tid + 3] = e0 + h0 + h1 + h2;
    }
    __syncthreads();

    // ---------- phase 0c: scatter to global sb AND LDS sxy ----------
    #pragma unroll
    for (int j = 0; j < 16; ++j) {
        const int p = j * FPS_T + tid;
        const float x = bx[p * 3 + 0], y = bx[p * 3 + 1], z = bx[p * 3 + 2];
        int cx = (int)(x * 16.0f); cx = cx > 15 ? 15 : (cx < 0 ? 0 : cx);
        int cy = (int)(y * 16.0f); cy = cy > 15 ? 15 : (cy < 0 ? 0 : cy);
        int cz = (int)(z * 16.0f); cz = cz > 15 ? 15 : (cz < 0 ? 0 : cz);
        int code = 0;
        #pragma unroll
        for (int i = 0; i < 4; ++i)
            code |= (((cx >> i) & 1) << (3 * i)) |
                    (((cy >> i) & 1) << (3 * i + 1)) |
                    (((cz >> i) & 1) << (3 * i + 2));
        const int slot = atomicAdd(&hist[code], 1);
        sb[slot]  = make_float4(x, y, z, __int_as_float(p));
        sxy[slot] = make_float2(x, y);
    }
    __syncthreads();   // drains scatter stores before readback

    // ---------- phase 0d: AABB + z/tb preload, per owned chunk ----------
#define DECLZ(k) float z##k; unsigned tb##k;
    REPEAT16(DECLZ)
#undef DECLZ
    float dreg[16];
    float abx0 = 0.f, aby0 = 0.f, abz0 = 0.f, abx1 = 0.f, aby1 = 0.f, abz1 = 0.f;

#define AABBPRE(k) { const int g = wv + ((k) << 4);                       \
    const float4 pt = sb[(g << 6) + lane];                                \
    z##k  = pt.z;                                                         \
    tb##k = 0x3FFFu - (unsigned)__float_as_int(pt.w);                     \
    dreg[k] = 1e10f;                                                      \
    float mnx = pt.x, mxx = pt.x, mny = pt.y, mxy = pt.y,                 \
          mnz = pt.z, mxz = pt.z;                                         \
    _Pragma("unroll")                                                     \
    for (int m = 32; m >= 1; m >>= 1) {                                   \
        mnx = fminf(mnx, __shfl_xor(mnx, m, 64));                         \
        mxx = fmaxf(mxx, __shfl_xor(mxx, m, 64));                         \
        mny = fminf(mny, __shfl_xor(mny, m, 64));                         \
        mxy = fmaxf(mxy, __shfl_xor(mxy, m, 64));                         \
        mnz = fminf(mnz, __shfl_xor(mnz, m, 64));                         \
        mxz = fmaxf(mxz, __shfl_xor(mxz, m, 64));                         \
    }                                                                     \
    if (lane == (k)) { abx0 = mnx; abx1 = mxx; aby0 = mny; aby1 = mxy;    \
                       abz0 = mnz; abz1 = mxz; } }
    REPEAT16(AABBPRE)
#undef AABBPRE

    if (tid == 0) { slotk[0] = 0ull; slotk[1] = 0ull; slotk[2] = 0ull; slotk[3] = 0ull; }
    __syncthreads();

    // ---------- main loop: ONE barrier per iteration ----------
    float ccx = bx[0], ccy = bx[1], ccz = bx[2];
    float prev_wd = 1e10f;
    float bestd = -1.0f;
    unsigned besttb = 0u;
    int bestk = 0;
    float* outb = new_xyz + (size_t)b * NPOINT * 3;

    for (int it = 0; it < NPOINT; ++it) {
        // pin z/tb registers: loop-carried -> compiler cannot remat as reloads
        asm volatile("" : "+v"(z0), "+v"(z1), "+v"(z2),  "+v"(z3),
                          "+v"(z4), "+v"(z5), "+v"(z6),  "+v"(z7),
                          "+v"(z8), "+v"(z9), "+v"(z10), "+v"(z11),
                          "+v"(z12), "+v"(z13), "+v"(z14), "+v"(z15));
        asm volatile("" : "+v"(tb0), "+v"(tb1), "+v"(tb2),  "+v"(tb3),
                          "+v"(tb4), "+v"(tb5), "+v"(tb6),  "+v"(tb7),
                          "+v"(tb8), "+v"(tb9), "+v"(tb10), "+v"(tb11),
                          "+v"(tb12), "+v"(tb13), "+v"(tb14), "+v"(tb15));

        if (tid == 0) {
            outb[it * 3 + 0] = ccx;
            outb[it * 3 + 1] = ccy;
            outb[it * 3 + 2] = ccz;
        }

        // --- AABB prune vs global radius (lane k -> chunk wv+16k) ---
        bool active = false;
        if (lane < 16) {
            const float dx = fmaxf(fmaxf(abx0 - ccx, ccx - abx1), 0.0f);
            const float dy = fmaxf(fmaxf(aby0 - ccy, ccy - aby1), 0.0f);
            const float dz = fmaxf(fmaxf(abz0 - ccz, ccz - abz1), 0.0f);
            const float mind2 = dx * dx + dy * dy + dz * dz;
            active = !(mind2 > prev_wd * 1.001f);
        }
        const unsigned umask = (unsigned)(__ballot(active) & 0xFFFFull);

        // --- update active owned chunks (LDS xy + pinned z) ---
        bool redo = ((umask >> bestk) & 1u) != 0u;
#define UPD(k) if (umask & (1u << (k))) {                                 \
            const int g = wv + ((k) << 4);                                \
            const float2 xy = sxy[(g << 6) + lane];                       \
            const float dx = xy.x - ccx;                                  \
            const float dy = xy.y - ccy;                                  \
            const float dz = z##k - ccz;                                  \
            const float t  = (dx * dx + dy * dy) + dz * dz;               \
            const float nd = fminf(dreg[k], t);                           \
            redo = redo || (nd == bestd && tb##k > besttb);               \
            dreg[k] = nd; }
        REPEAT16(UPD)
#undef UPD

        // --- per-lane best over 16 owned points (only when invalidated) ---
        if (redo) {
            bestd = -1.0f; besttb = 0u; bestk = 0;
#define LM(k) { const bool gt = (dreg[k] > bestd) ||                      \
                    (dreg[k] == bestd && tb##k > besttb);                 \
                bestd  = gt ? dreg[k] : bestd;                            \
                besttb = gt ? tb##k   : besttb;                           \
                bestk  = gt ? (k)     : bestk; }
            REPEAT16(LM)
#undef LM
        }

        // --- wave reduce: one f32 butterfly (+ rare exact-tie path) ---
        float m = bestd;
        #pragma unroll
        for (int s = 32; s >= 1; s >>= 1)
            m = fmaxf(m, __shfl_xor(m, s, 64));
        unsigned long long tied = __ballot(bestd == m);
        if (__popcll(tied) > 1) {
            unsigned v = (bestd == m) ? besttb : 0u;
            #pragma unroll
            for (int s = 32; s >= 1; s >>= 1) {
                const unsigned o = (unsigned)__shfl_xor((int)v, s, 64);
                v = o > v ? o : v;
            }
            tied = __ballot(bestd == m && besttb == v);
        }
        const int wl = __ffsll((long long)tied) - 1;
        const unsigned wtb = (unsigned)__shfl((int)besttb, wl, 64);

        if (lane == wl) {
            const int s = ((wv + (bestk << 4)) << 6) + lane;
            const float2 xy = sxy[s];
            float zz = z0;
#define ZS(k) zz = (bestk == (k)) ? z##k : zz;
            REPEAT16(ZS)
#undef ZS
            ubc[(it & 1) * 16 + wv] = make_float4(xy.x, xy.y, zz, 0.0f);
        }
        if (lane == 0) {
            const unsigned long long key =
                (((unsigned long long)__float_as_uint(m)) << 32) |
                ((unsigned long long)wtb << 4) | (unsigned long long)wv;
            atomicMax(&slotk[it & 3], key);
        }
        if (tid == 0) slotk[(it + 1) & 3] = 0ull;
        __syncthreads();

        // --- winner broadcast: slot key -> wave id -> coords (LDS only) ---
        const unsigned long long wk = slotk[it & 3];
        prev_wd = __uint_as_float((unsigned)(wk >> 32));
        const int wwv = (int)(wk & 0xFull);
        const float4 win = ubc[(it & 1) * 16 + wwv];
        ccx = win.x; ccy = win.y; ccz = win.z;
    }
}

// ---------------------------------------------------------------------------
// K2: Ball query. One wave per query; ordered first-32 selection via ballot,
// early exit once 32 found. Exact arithmetic (contract off, rad2 = (float)0.04).
// ---------------------------------------------------------------------------
__global__ __launch_bounds__(256) void ballq_kernel(const float* __restrict__ xyz,
                                                    const float* __restrict__ new_xyz,
                                                    int* __restrict__ gidx) {
    #pragma clang fp contract(off)
    const int lane = threadIdx.x & 63;
    const int q    = blockIdx.x * 4 + (threadIdx.x >> 6);
    const int b    = q >> 10;                  // NPOINT = 1024
    const float* bx = xyz + (size_t)b * NN * 3;
    const float* nx = new_xyz + (size_t)q * 3;
    const float cx = nx[0], cy = nx[1], cz = nx[2];
    const float rad2 = 0.04f;  // f32 cast of python double 0.2**2 — NOT 0.2f*0.2f

    int* out  = gidx + (size_t)q * NSAMPLE;
    int taken = 0;
    int first = NN - 1;

    for (int chunk = 0; chunk < NN / 64 && taken < NSAMPLE; ++chunk) {
        const int   i  = chunk * 64 + lane;
        const float dx = cx - bx[i * 3 + 0];
        const float dy = cy - bx[i * 3 + 1];
        const float dz = cz - bx[i * 3 + 2];
        const float t  = dx * dx + dy * dy + dz * dz;
        const bool ok  = !(t > rad2);
        const unsigned long long m = __ballot(ok);
        const int cnt = __popcll(m);
        if (taken == 0 && cnt > 0) first = chunk * 64 + (__ffsll((long long)m) - 1);
        if (ok) {
            const int rank = taken + __popcll(m & ((1ull << lane) - 1ull));
            if (rank < NSAMPLE) out[rank] = i;
        }
        taken += cnt;
    }
    const int sat = taken < NSAMPLE ? taken : NSAMPLE;
    if (lane >= sat && lane < NSAMPLE) out[lane] = (taken > 0) ? first : (NN - 1);
}

// ---------------------------------------------------------------------------
// K3: gather feats -> LDS, MLP1 (67->64) + relu, MLP2 (64->128) + relu,
// max over the 32 samples. One 256-thread block per query. FMA allowed.
// ---------------------------------------------------------------------------
__global__ __launch_bounds__(256) void mlp_kernel(const float* __restrict__ xyz,
                                                  const float* __restrict__ points,
                                                  const float* __restrict__ w1,
                                                  const float* __restrict__ b1,
                                                  const float* __restrict__ w2,
                                                  const float* __restrict__ b2,
                                                  const float* __restrict__ new_xyz,
                                                  const int*   __restrict__ gidx,
                                                  float* __restrict__ new_points) {
    __shared__ __align__(16) float feats[32][68];
    __shared__ __align__(16) float h1s[32][64];
    __shared__ float pmax[2][128];

    const int q = blockIdx.x;
    const int b = q >> 10;
    const int t = threadIdx.x;

    {
        const int k  = t >> 3;
        const int l8 = t & 7;
        const int gi = gidx[q * 32 + k];
        const float* prow = points + ((size_t)b * NN + gi) * CC;
        const float4 v0 = *(const float4*)(prow + l8 * 8);
        const float4 v1 = *(const float4*)(prow + l8 * 8 + 4);
        *(float4*)&feats[k][4 + l8 * 8] = v0;
        *(float4*)&feats[k][8 + l8 * 8] = v1;
        if (l8 == 0) {
            const float* pr = xyz + ((size_t)b * NN + gi) * 3;
            const float* nr = new_xyz + (size_t)q * 3;
            feats[k][0] = pr[0] - nr[0];
            feats[k][1] = pr[1] - nr[1];
            feats[k][2] = pr[2] - nr[2];
        }
    }

    const int c1 = t & 63;
    float w1r[67];
    #pragma unroll
    for (int j = 0; j < 67; ++j) w1r[j] = w1[c1 * 67 + j];
    const float bb1 = b1[c1];
    __syncthreads();

    const int kg = t >> 6;
    #pragma unroll
    for (int kk = 0; kk < 8; ++kk) {
        const int kr = kg * 8 + kk;
        float acc = bb1;
        acc += feats[kr][0] * w1r[0] + feats[kr][1] * w1r[1] + feats[kr][2] * w1r[2];
        #pragma unroll
        for (int j = 0; j < 64; j += 4) {
            const float4 f = *(const float4*)&feats[kr][4 + j];
            acc += f.x * w1r[3 + j] + f.y * w1r[4 + j] + f.z * w1r[5 + j] + f.w * w1r[6 + j];
        }
        h1s[kr][c1] = fmaxf(acc, 0.0f);
    }

    const int o2 = t & 127;
    const int kh = t >> 7;
    float w2r[64];
    #pragma unroll
    for (int j = 0; j < 64; ++j) w2r[j] = w2[o2 * 64 + j];
    const float bb2 = b2[o2];
    __syncthreads();

    float mx = -INFINITY;
    #pragma unroll
    for (int kk = 0; kk < 16; ++kk) {
        const int kr = kh * 16 + kk;
        float acc = bb2;
        #pragma unroll
        for (int j = 0; j < 64; j += 4) {
            const float4 h = *(const float4*)&h1s[kr][j];
            acc += h.x * w2r[j] + h.y * w2r[j + 1] + h.z * w2r[j + 2] + h.w * w2r[j + 3];
        }
        mx = fmaxf(mx, fmaxf(acc, 0.0f));
    }
    pmax[kh][o2] = mx;
    __syncthreads();
    if (t < 128) {
        new_points[(size_t)q * 128 + t] = fmaxf(pmax[0][t], pmax[1][t]);
    }
}

// ---------------------------------------------------------------------------
extern "C" void kernel_launch(void* const* d_in, const int* in_sizes, int n_in,
                              void* d_out, int out_size, void* d_ws, size_t ws_size,
                              hipStream_t stream) {
    const float* xyz    = (const float*)d_in[0];
    const float* points = (const float*)d_in[1];
    const float* w1     = (const float*)d_in[2];
    const float* b1     = (const float*)d_in[3];
    const float* w2     = (const float*)d_in[4];
    const float* b2     = (const float*)d_in[5];

    float* out_newxyz    = (float*)d_out;
    float* out_newpoints = (float*)d_out + (size_t)BB * NPOINT * 3;
    int*    gidx    = (int*)d_ws;                                   // 512 KB
    float4* sortbuf = (float4*)((char*)d_ws + (size_t)512 * 1024);  // 1 MB

    // dynamic LDS: slotk 32 + ubc 512 + wsum 64 + sxy 131072 + hist 16384
    const int fps_lds = 32 + 512 + 64 + 131072 + 16384;   // 148064 B
    (void)hipFuncSetAttribute((const void*)fps_kernel,
                              hipFuncAttributeMaxDynamicSharedMemorySize,
                              fps_lds);

    fps_kernel<<<BB, FPS_T, fps_lds, stream>>>(xyz, out_newxyz, sortbuf);
    ballq_kernel<<<(BB * NPOINT) / 4, 256, 0, stream>>>(xyz, out_newxyz, gidx);
    mlp_kernel<<<BB * NPOINT, 256, 0, stream>>>(xyz, points, w1, b1, w2, b2,
                                                out_newxyz, gidx, out_newpoints);
}